// Round 1
// baseline (110.952 us; speedup 1.0000x reference)
//
#include <hip/hip_runtime.h>

#define THREADS 256
#define ROWS 4
#define PI_F 3.14159265358979323846f
#define NPAD(i) ((i) + ((i) >> 5))

// 4096 complex rows (pairs of real rows packed Re/Im), 4 rows per block -> 1024 blocks.
// Each block: load 4 rows (zero-padded to 1024) into LDS, DIF FFT (nat->BR),
// multiply by bit-reversed ramp filter (* 1/1024 normalization), DIT IFFT (BR->nat),
// store first 512 samples with the reference's scrambled proj.T.reshape layout.
__global__ __launch_bounds__(THREADS, 4) void fbp_butterfly_kernel(
    const float* __restrict__ x,
    const float* __restrict__ filt_br,
    float* __restrict__ out) {
  __shared__ float2 data[ROWS][1056];  // 1024 + pad(32) per row

  const int t = threadIdx.x;
  const int blk = blockIdx.x;
  const int bc = blk >> 6;           // 16 (b,c) groups, 64 blocks each
  const int p0 = (blk & 63) << 2;    // a-pair base (4 pairs per block)

  const float2* __restrict__ x2 = (const float2*)x;
  float2* __restrict__ out2 = (float2*)out;

  // ---- load: x[(bc*512+s)*512 + a], a = 2*(p0+r) -> float2 (row a = Re, row a+1 = Im)
  #pragma unroll
  for (int k = 0; k < 16; ++k) {
    int u = t + (k << 8);
    int r = u & 3;
    int s = u >> 2;  // 0..1023
    float2 v = make_float2(0.f, 0.f);
    if (s < 512) v = x2[(bc * 512 + s) * 256 + p0 + r];
    data[r][NPAD(s)] = v;
  }
  __syncthreads();

  // ---- forward FFT: DIF, natural -> bit-reversed, w = exp(-i*pi*j/h)
  for (int h = 512; h >= 1; h >>= 1) {
    float c0, s0;
    {
      int j = t & (h - 1);
      float ang = -PI_F * (float)j / (float)h;
      __sincosf(ang, &s0, &c0);
    }
    float c1 = c0, s1 = s0;
    if (h == 512) {
      float ang = -PI_F * (float)(t + 256) / 512.0f;
      __sincosf(ang, &s1, &c1);
    }
    #pragma unroll
    for (int w = 0; w < 2; ++w) {
      int p = t + (w << 8);          // butterfly index within row, 0..511
      int j = p & (h - 1);
      int i0 = 2 * p - j;            // g*2h + j
      int a0 = NPAD(i0);
      int a1 = NPAD(i0 + h);
      float c = w ? c1 : c0;
      float sn = w ? s1 : s0;
      #pragma unroll
      for (int r = 0; r < ROWS; ++r) {
        float2 u2 = data[r][a0];
        float2 v2 = data[r][a1];
        data[r][a0] = make_float2(u2.x + v2.x, u2.y + v2.y);
        float dx = u2.x - v2.x;
        float dy = u2.y - v2.y;
        data[r][a1] = make_float2(dx * c - dy * sn, dx * sn + dy * c);
      }
    }
    __syncthreads();
  }

  // ---- filter in bit-reversed order, fold in the 1/1024 normalization
  #pragma unroll
  for (int k = 0; k < 16; ++k) {
    int u = t + (k << 8);
    int r = u & 3;
    int i = u >> 2;  // 0..1023
    float f = filt_br[i] * (1.0f / 1024.0f);
    int ai = NPAD(i);
    float2 v = data[r][ai];
    data[r][ai] = make_float2(v.x * f, v.y * f);
  }
  __syncthreads();

  // ---- inverse FFT: DIT, bit-reversed -> natural, w = exp(+i*pi*j/h)
  for (int h = 1; h <= 512; h <<= 1) {
    float c0, s0;
    {
      int j = t & (h - 1);
      float ang = PI_F * (float)j / (float)h;
      __sincosf(ang, &s0, &c0);
    }
    float c1 = c0, s1 = s0;
    if (h == 512) {
      float ang = PI_F * (float)(t + 256) / 512.0f;
      __sincosf(ang, &s1, &c1);
    }
    #pragma unroll
    for (int w = 0; w < 2; ++w) {
      int p = t + (w << 8);
      int j = p & (h - 1);
      int i0 = 2 * p - j;
      int a0 = NPAD(i0);
      int a1 = NPAD(i0 + h);
      float c = w ? c1 : c0;
      float sn = w ? s1 : s0;
      #pragma unroll
      for (int r = 0; r < ROWS; ++r) {
        float2 u2 = data[r][a0];
        float2 v2 = data[r][a1];
        float vx = v2.x * c - v2.y * sn;
        float vy = v2.x * sn + v2.y * c;
        data[r][a0] = make_float2(u2.x + vx, u2.y + vy);
        data[r][a1] = make_float2(u2.x - vx, u2.y - vy);
      }
    }
    __syncthreads();
  }

  // ---- store: reference does proj.T.reshape(b,c,s,a) which is a scrambled
  // reinterpretation. Value (row bc,a'=2*(p0+r), sample s) goes to flat float idx:
  //   262144*(s>>5) + 512*(16*(s&31) + bc) + a'     (float2 idx = that/2)
  #pragma unroll
  for (int k = 0; k < 8; ++k) {
    int u = t + (k << 8);
    int r = u & 3;
    int s = u >> 2;  // 0..511
    int o2 = 131072 * (s >> 5) + 256 * (16 * (s & 31) + bc) + p0 + r;
    out2[o2] = data[r][NPAD(s)];
  }
}

extern "C" void kernel_launch(void* const* d_in, const int* in_sizes, int n_in,
                              void* d_out, int out_size, void* d_ws, size_t ws_size,
                              hipStream_t stream) {
  const float* x = (const float*)d_in[0];
  // d_in[1] = twiddle_fft, d_in[2] = twiddle_ifft (recomputed on the fly)
  const float* filt = (const float*)d_in[3];
  float* out = (float*)d_out;
  (void)in_sizes; (void)n_in; (void)out_size; (void)d_ws; (void)ws_size;

  hipLaunchKernelGGL(fbp_butterfly_kernel, dim3(1024), dim3(THREADS), 0, stream,
                     x, filt, out);
}

// Round 2
// 91.784 us; speedup vs baseline: 1.2088x; 1.2088x over previous
//
#include <hip/hip_runtime.h>

#define THREADS 256
#define PI_F 3.14159265358979323846f
// pad 2 float2 per 16 elements: breaks power-of-2 bank strides, keeps 16B
// alignment for float4 access at P(4t) (byte off = 32t + 16*(t>>2))
#define P(i) ((i) + (((i) >> 4) << 1))

__device__ __forceinline__ float2 cadd(float2 a, float2 b) { return make_float2(a.x + b.x, a.y + b.y); }
__device__ __forceinline__ float2 csub(float2 a, float2 b) { return make_float2(a.x - b.x, a.y - b.y); }
__device__ __forceinline__ float2 cmul(float2 a, float2 b) {
  return make_float2(a.x * b.x - a.y * b.y, a.x * b.y + a.y * b.x);
}
__device__ __forceinline__ float2 cscale(float2 a, float s) { return make_float2(a.x * s, a.y * s); }

// One radix-4 round = two radix-2 stages (strides 2q and q for FWD, q and 2q for INV).
// Thread t handles group base = (t>>SHIFT)*4q + (t&(q-1)), elements {base, +q, +2q, +3q}.
// In-place, read-set == write-set per thread -> one barrier per round (outside).
template <int SHIFT, bool INV>
__device__ __forceinline__ void radix4_round(float2 (*data)[1152], int t) {
  const int q = 1 << SHIFT;
  const int j = t & (q - 1);
  const int g = t >> SHIFT;
  const int base = (g << (SHIFT + 2)) + j;
  float c1, s1;
  __sincosf((INV ? PI_F : -PI_F) * (float)j / (float)(2 * q), &s1, &c1);
  const float2 w1 = make_float2(c1, s1);
  const float2 w2 = cmul(w1, w1);
  const int i0 = P(base), i1 = P(base + q), i2 = P(base + 2 * q), i3 = P(base + 3 * q);
  float2 va[4], vb[4], vc[4], vd[4];
#pragma unroll
  for (int r = 0; r < 4; ++r) {
    va[r] = data[r][i0]; vb[r] = data[r][i1]; vc[r] = data[r][i2]; vd[r] = data[r][i3];
  }
#pragma unroll
  for (int r = 0; r < 4; ++r) {
    float2 o0, o1, o2, o3;
    if (!INV) {
      // DIF: stage h=2q then stage q; w(j+q, 2q) = -i*w1
      float2 A  = cadd(va[r], vc[r]);
      float2 Cm = cmul(csub(va[r], vc[r]), w1);
      float2 B  = cadd(vb[r], vd[r]);
      float2 Dm = cmul(csub(vb[r], vd[r]), make_float2(s1, -c1));  // *( -i*w1 )
      o0 = cadd(A, B);
      o1 = cmul(csub(A, B), w2);
      o2 = cadd(Cm, Dm);
      o3 = cmul(csub(Cm, Dm), w2);
    } else {
      // DIT: stage q (tw = w1^2) then stage 2q (tw = w1 and i*w1)
      float2 tb = cmul(vb[r], w2), td = cmul(vd[r], w2);
      float2 a1 = cadd(va[r], tb), b1 = csub(va[r], tb);
      float2 cc = cadd(vc[r], td), dd = csub(vc[r], td);
      float2 tc = cmul(cc, w1);
      float2 te = cmul(dd, make_float2(-s1, c1));  // *( i*w1 )
      o0 = cadd(a1, tc);
      o2 = csub(a1, tc);
      o1 = cadd(b1, te);
      o3 = csub(b1, te);
    }
    data[r][i0] = o0; data[r][i1] = o1; data[r][i2] = o2; data[r][i3] = o3;
  }
}

// 4096 complex rows (adjacent-a real rows packed Re/Im), 4 rows/block, 1024 blocks.
// n=1024 = 4^5: 5 fwd radix-4 rounds (nat->BR), filter in BR order, 5 inv rounds.
// Fusions: round1 absorbs zero-padding (2 loads); fwd-round5+filter+inv-round1 in
// registers (same 4 consecutive elements); inv-round5 emits only s<512.
__global__ __launch_bounds__(THREADS, 4) void fbp_butterfly_r4(
    const float* __restrict__ x,
    const float* __restrict__ filt_br,
    float* __restrict__ out) {
  __shared__ __align__(16) float2 data[4][1152];  // 1024 + 128 pad per row, 36 KB

  const int t = threadIdx.x;
  const int blk = blockIdx.x;
  const int bc = blk >> 6;         // 16 (b,c) groups
  const int p0 = (blk & 63) << 2;  // a-pair base, 4 pairs/block

  const float2* __restrict__ x2 = (const float2*)x;
  float2* __restrict__ out2 = (float2*)out;

  // ---- staging in: coalesced, 512 samples x 4 rows
#pragma unroll
  for (int k = 0; k < 8; ++k) {
    int u = t + (k << 8);
    int r = u & 3;
    int s = u >> 2;  // 0..511
    data[r][P(s)] = x2[(bc * 512 + s) * 256 + p0 + r];
  }
  __syncthreads();

  // ---- fwd round 1 (stages 512,256), inputs 512..1023 are zero
  {
    float c1, s1;
    __sincosf(-PI_F * (float)t / 512.0f, &s1, &c1);
    const float2 w1 = make_float2(c1, s1);
    const float2 w2 = cmul(w1, w1);
    const int i0 = P(t), i1 = P(t + 256), i2 = P(t + 512), i3 = P(t + 768);
    float2 va[4], vb[4];
#pragma unroll
    for (int r = 0; r < 4; ++r) { va[r] = data[r][i0]; vb[r] = data[r][i1]; }
#pragma unroll
    for (int r = 0; r < 4; ++r) {
      float2 a = va[r], b = vb[r];
      float2 Cm = cmul(a, w1);
      float2 Dm = cmul(b, make_float2(s1, -c1));
      data[r][i0] = cadd(a, b);
      data[r][i1] = cmul(csub(a, b), w2);
      data[r][i2] = cadd(Cm, Dm);
      data[r][i3] = cmul(csub(Cm, Dm), w2);
    }
  }
  __syncthreads();

  radix4_round<6, false>(data, t);  // stages 128,64
  __syncthreads();
  radix4_round<4, false>(data, t);  // stages 32,16
  __syncthreads();
  radix4_round<2, false>(data, t);  // stages 8,4
  __syncthreads();

  // ---- fused: fwd round 5 (stages 2,1) + BR-order filter + inv round 1 (stages 1,2)
  {
    const float4 f4 = ((const float4*)filt_br)[t];  // filt_br[4t..4t+3]
    const float sc = 1.0f / 1024.0f;                // unitary fwd+inv normalization
    const int ib = P(4 * t);
#pragma unroll
    for (int r = 0; r < 4; ++r) {
      float4* p = (float4*)&data[r][ib];  // 4 consecutive complex, 16B-aligned
      float4 lo = p[0], hi = p[1];
      float2 a = make_float2(lo.x, lo.y), b = make_float2(lo.z, lo.w);
      float2 c = make_float2(hi.x, hi.y), d = make_float2(hi.z, hi.w);
      // fwd stages h=2 then h=1 (all twiddles trivial)
      float2 A  = cadd(a, c), Cm = csub(a, c);
      float2 B  = cadd(b, d);
      float2 Dm = make_float2(b.y - d.y, d.x - b.x);  // (b-d)*(-i)
      float2 o0 = cadd(A, B), o1 = csub(A, B), o2 = cadd(Cm, Dm), o3 = csub(Cm, Dm);
      // ramp filter, bit-reversed order == storage order here
      o0 = cscale(o0, f4.x * sc);
      o1 = cscale(o1, f4.y * sc);
      o2 = cscale(o2, f4.z * sc);
      o3 = cscale(o3, f4.w * sc);
      // inv stages h=1 then h=2
      float2 a1 = cadd(o0, o1), b1 = csub(o0, o1);
      float2 cc = cadd(o2, o3), dd = csub(o2, o3);
      float2 te = make_float2(-dd.y, dd.x);  // i*dd
      float2 r0 = cadd(a1, cc), r2 = csub(a1, cc);
      float2 r1 = cadd(b1, te), r3 = csub(b1, te);
      p[0] = make_float4(r0.x, r0.y, r1.x, r1.y);
      p[1] = make_float4(r2.x, r2.y, r3.x, r3.y);
    }
  }
  __syncthreads();

  radix4_round<2, true>(data, t);  // stages 4,8
  __syncthreads();
  radix4_round<4, true>(data, t);  // stages 16,32
  __syncthreads();
  radix4_round<6, true>(data, t);  // stages 64,128
  __syncthreads();

  // ---- inv round 5 (stages 256,512): only outputs s<512 needed
  {
    float c1, s1;
    __sincosf(PI_F * (float)t / 512.0f, &s1, &c1);
    const float2 w1 = make_float2(c1, s1);
    const float2 w2 = cmul(w1, w1);
    const float2 iw1 = make_float2(-s1, c1);  // i*w1
    const int i0 = P(t), i1 = P(t + 256), i2 = P(t + 512), i3 = P(t + 768);
    float2 va[4], vb[4], vc[4], vd[4];
#pragma unroll
    for (int r = 0; r < 4; ++r) {
      va[r] = data[r][i0]; vb[r] = data[r][i1]; vc[r] = data[r][i2]; vd[r] = data[r][i3];
    }
#pragma unroll
    for (int r = 0; r < 4; ++r) {
      float2 tb = cmul(vb[r], w2), td = cmul(vd[r], w2);
      float2 a1 = cadd(va[r], tb), b1 = csub(va[r], tb);
      float2 cc = cadd(vc[r], td), dd = csub(vc[r], td);
      data[r][i0] = cadd(a1, cmul(cc, w1));   // sample t
      data[r][i1] = cadd(b1, cmul(dd, iw1));  // sample t+256
    }
  }
  __syncthreads();

  // ---- store: scrambled proj.T.reshape layout (validated in R1):
  // sample s of row (bc, a'=2*(p0+r)) -> float2 idx 131072*(s>>5) + 256*(16*(s&31)+bc) + p0+r
#pragma unroll
  for (int k = 0; k < 8; ++k) {
    int u = t + (k << 8);
    int r = u & 3;
    int s = u >> 2;  // 0..511
    int o2 = 131072 * (s >> 5) + 256 * (16 * (s & 31) + bc) + p0 + r;
    out2[o2] = data[r][P(s)];
  }
}

extern "C" void kernel_launch(void* const* d_in, const int* in_sizes, int n_in,
                              void* d_out, int out_size, void* d_ws, size_t ws_size,
                              hipStream_t stream) {
  const float* x = (const float*)d_in[0];
  // d_in[1] = twiddle_fft, d_in[2] = twiddle_ifft (recomputed on the fly)
  const float* filt = (const float*)d_in[3];
  float* out = (float*)d_out;
  (void)in_sizes; (void)n_in; (void)out_size; (void)d_ws; (void)ws_size;

  hipLaunchKernelGGL(fbp_butterfly_r4, dim3(1024), dim3(THREADS), 0, stream,
                     x, filt, out);
}

// Round 3
// 91.067 us; speedup vs baseline: 1.2184x; 1.0079x over previous
//
#include <hip/hip_runtime.h>

#define THREADS 256
#define PI_F 3.14159265358979323846f
// pad +2 float2 per 32: makes idx-stride-64 map to bank-stride 68 (=4 mod 16,
// uniform for the 4x4 tile patterns) and keeps P(16u) even (16B-aligned b128).
#define P(i) ((i) + (((i) >> 5) << 1))
#define ROWSZ 1092  // >= P(1023)+1 = 1086, even, == 4 mod 16 (spreads row bases)

__device__ __forceinline__ float2 cadd(float2 a, float2 b) { return make_float2(a.x + b.x, a.y + b.y); }
__device__ __forceinline__ float2 csub(float2 a, float2 b) { return make_float2(a.x - b.x, a.y - b.y); }
__device__ __forceinline__ float2 cmul(float2 a, float2 b) {
  return make_float2(a.x * b.x - a.y * b.y, a.x * b.y + a.y * b.x);
}
__device__ __forceinline__ float2 cscale(float2 a, float s) { return make_float2(a.x * s, a.y * s); }

// In-place radix-4 butterfly on positions (p, p+q, p+2q, p+3q) = (a,b,c,d).
// FWD: DIF stages h=2q then h=q. INV: DIT stages h=q then h=2q. w1 = exp(∓iπj/2q).
template <bool INV>
__device__ __forceinline__ void bf4(float2& a, float2& b, float2& c, float2& d, float2 w1) {
  const float2 w2 = cmul(w1, w1);
  if (!INV) {
    float2 A = cadd(a, c), Cm = cmul(csub(a, c), w1);
    float2 B = cadd(b, d), Dm = cmul(csub(b, d), make_float2(w1.y, -w1.x));  // *(-i w1)
    a = cadd(A, B); b = cmul(csub(A, B), w2);
    c = cadd(Cm, Dm); d = cmul(csub(Cm, Dm), w2);
  } else {
    float2 tb = cmul(b, w2), td = cmul(d, w2);
    float2 a1 = cadd(a, tb), b1 = csub(a, tb);
    float2 cc = cadd(c, td), dd = csub(c, td);
    float2 tc = cmul(cc, w1), te = cmul(dd, make_float2(-w1.y, w1.x));  // *(i w1)
    a = cadd(a1, tc); c = csub(a1, tc);
    b = cadd(b1, te); d = csub(b1, te);
  }
}

// Block = 256 threads = 4 waves; wave w owns row w (1024 complex) -> all five
// LDS round-trips are wave-private (no barriers; lgkmcnt only). 2 barriers total.
// Each thread: 16 elements as a 4x4 register tile = 2 radix-4 rounds per trip.
__global__ __launch_bounds__(THREADS, 4) void fbp_butterfly_wv(
    const float* __restrict__ x,
    const float* __restrict__ filt_br,
    float* __restrict__ out) {
  __shared__ __align__(16) float2 data[4][ROWSZ];  // 34,944 B -> 4 blocks/CU

  const int t = threadIdx.x;
  const int blk = blockIdx.x;
  // XCD-aware swizzle: the two blocks sharing each 64B x-line (a-pair blocks 2m,
  // 2m+1) get the same blk%8 -> same XCD L2 -> line fetched once.
  const int xx = blk & 7, yy = blk >> 3;
  const int L = xx + ((yy >> 1) << 3);                 // 0..511 line index
  const int bc = L >> 5;                               // 16 (b,c) groups
  const int p0 = (((L & 31) << 1) + (yy & 1)) << 2;    // a-pair base, 4 pairs/block

  const float2* __restrict__ x2 = (const float2*)x;
  float2* __restrict__ out2 = (float2*)out;

  // ---- staging in: coalesced 32B chunks, only s<512 (rest implicit zero)
#pragma unroll
  for (int k = 0; k < 8; ++k) {
    int u2 = t + (k << 8);
    int r = u2 & 3, s = u2 >> 2;  // 0..511
    data[r][P(s)] = x2[(bc * 512 + s) * 256 + p0 + r];
  }
  __syncthreads();

  const int w = t >> 6;   // wave = row
  const int u = t & 63;
  float2* __restrict__ row = data[w];

  const float2 E8[4]  = {{1.f, 0.f}, {0.92387953f, -0.38268343f},
                         {0.70710678f, -0.70710678f}, {0.38268343f, -0.92387953f}};
  const float2 E8c[4] = {{1.f, 0.f}, {0.92387953f, 0.38268343f},
                         {0.70710678f, 0.70710678f}, {0.38268343f, 0.92387953f}};

  float2 v[4][4];  // v[k][l] <-> element u + 64k + 256l (trips A/E) or tile B/D

  // ======== Trip A: fwd rounds q=256 (h=512,256; zero-padded) + q=64 (h=128,64)
  {
    float ss, sc;
    __sincosf(-PI_F * (float)u / 512.0f, &ss, &sc);
    const float2 wu = make_float2(sc, ss);  // exp(-i pi u/512)
#pragma unroll
    for (int k = 0; k < 4; ++k) {
      float2 a = row[P(u + 64 * k)];
      float2 b = row[P(u + 64 * k + 256)];
      const float2 w1 = cmul(wu, E8[k]);  // exp(-i pi (u+64k)/512)
      const float2 w2 = cmul(w1, w1);
      float2 Cm = cmul(a, w1);
      float2 Dm = cmul(b, make_float2(w1.y, -w1.x));
      v[k][0] = cadd(a, b);
      v[k][1] = cmul(csub(a, b), w2);
      v[k][2] = cadd(Cm, Dm);
      v[k][3] = cmul(csub(Cm, Dm), w2);
    }
    float s2, c2;
    __sincosf(-PI_F * (float)u / 128.0f, &s2, &c2);
    const float2 w64 = make_float2(c2, s2);
#pragma unroll
    for (int l = 0; l < 4; ++l) bf4<false>(v[0][l], v[1][l], v[2][l], v[3][l], w64);
#pragma unroll
    for (int k = 0; k < 4; ++k)
#pragma unroll
      for (int l = 0; l < 4; ++l) row[P(u + 64 * k + 256 * l)] = v[k][l];
  }

  // ======== Trip B: fwd rounds q=16 (h=32,16) + q=4 (h=8,4)
  {
    const int g = u >> 2, j3 = u & 3;
    const int base = (g << 6) + j3;  // + 4k + 16l
#pragma unroll
    for (int k = 0; k < 4; ++k)
#pragma unroll
      for (int l = 0; l < 4; ++l) v[k][l] = row[P(base + 4 * k + 16 * l)];
    float sb, cb;
    __sincosf(-PI_F * (float)j3 / 32.0f, &sb, &cb);
    const float2 wj = make_float2(cb, sb);
#pragma unroll
    for (int k = 0; k < 4; ++k) {
      const float2 w1 = cmul(wj, E8[k]);  // exp(-i pi (4k+j3)/32)
      bf4<false>(v[k][0], v[k][1], v[k][2], v[k][3], w1);
    }
    float sq, cq;
    __sincosf(-PI_F * (float)j3 / 8.0f, &sq, &cq);
    const float2 w4 = make_float2(cq, sq);
#pragma unroll
    for (int l = 0; l < 4; ++l) bf4<false>(v[0][l], v[1][l], v[2][l], v[3][l], w4);
#pragma unroll
    for (int k = 0; k < 4; ++k)
#pragma unroll
      for (int l = 0; l < 4; ++l) row[P(base + 4 * k + 16 * l)] = v[k][l];
  }

  // ======== Trip C: 16 consecutive: fwd h=2,1 + BR filter (+1/1024) + inv h=1,2
  {
    const int base = u << 4;
    float4* rp = (float4*)&row[P(base)];  // P contiguous over [16u,16u+15], even
    const float4* f4p = (const float4*)filt_br;
    const float sc = 1.0f / 1024.0f;
#pragma unroll
    for (int c = 0; c < 4; ++c) {
      float4 lo = rp[2 * c], hi = rp[2 * c + 1];
      float2 a = make_float2(lo.x, lo.y), b = make_float2(lo.z, lo.w);
      float2 cq = make_float2(hi.x, hi.y), d = make_float2(hi.z, hi.w);
      // fwd h=2 then h=1 (trivial twiddles)
      float2 A = cadd(a, cq), Cm = csub(a, cq);
      float2 B = cadd(b, d);
      float2 Dm = make_float2(b.y - d.y, d.x - b.x);  // (b-d)*(-i)
      float2 o0 = cadd(A, B), o1 = csub(A, B), o2 = cadd(Cm, Dm), o3 = csub(Cm, Dm);
      const float4 f = f4p[(u << 2) + c];
      o0 = cscale(o0, f.x * sc); o1 = cscale(o1, f.y * sc);
      o2 = cscale(o2, f.z * sc); o3 = cscale(o3, f.w * sc);
      // inv h=1 then h=2
      float2 a1 = cadd(o0, o1), b1 = csub(o0, o1);
      float2 cc = cadd(o2, o3), dd = csub(o2, o3);
      float2 te = make_float2(-dd.y, dd.x);  // i*dd
      float2 r0 = cadd(a1, cc), r2 = csub(a1, cc);
      float2 r1 = cadd(b1, te), r3 = csub(b1, te);
      rp[2 * c] = make_float4(r0.x, r0.y, r1.x, r1.y);
      rp[2 * c + 1] = make_float4(r2.x, r2.y, r3.x, r3.y);
    }
  }

  // ======== Trip D: inv rounds q=4 (h=4,8) + q=16 (h=16,32)
  {
    const int g = u >> 2, j3 = u & 3;
    const int base = (g << 6) + j3;
#pragma unroll
    for (int k = 0; k < 4; ++k)
#pragma unroll
      for (int l = 0; l < 4; ++l) v[k][l] = row[P(base + 4 * k + 16 * l)];
    float sq, cq;
    __sincosf(PI_F * (float)j3 / 8.0f, &sq, &cq);
    const float2 w4 = make_float2(cq, sq);
#pragma unroll
    for (int l = 0; l < 4; ++l) bf4<true>(v[0][l], v[1][l], v[2][l], v[3][l], w4);
    float sb, cb;
    __sincosf(PI_F * (float)j3 / 32.0f, &sb, &cb);
    const float2 wj = make_float2(cb, sb);
#pragma unroll
    for (int k = 0; k < 4; ++k) {
      const float2 w1 = cmul(wj, E8c[k]);  // exp(+i pi (4k+j3)/32)
      bf4<true>(v[k][0], v[k][1], v[k][2], v[k][3], w1);
    }
#pragma unroll
    for (int k = 0; k < 4; ++k)
#pragma unroll
      for (int l = 0; l < 4; ++l) row[P(base + 4 * k + 16 * l)] = v[k][l];
  }

  // ======== Trip E: inv rounds q=64 (h=64,128) + q=256 (h=256,512; s<512 only)
  {
#pragma unroll
    for (int k = 0; k < 4; ++k)
#pragma unroll
      for (int l = 0; l < 4; ++l) v[k][l] = row[P(u + 64 * k + 256 * l)];
    float s2, c2;
    __sincosf(PI_F * (float)u / 128.0f, &s2, &c2);
    const float2 w64 = make_float2(c2, s2);
#pragma unroll
    for (int l = 0; l < 4; ++l) bf4<true>(v[0][l], v[1][l], v[2][l], v[3][l], w64);
    float ss, sc;
    __sincosf(PI_F * (float)u / 512.0f, &ss, &sc);
    const float2 wu = make_float2(sc, ss);  // exp(+i pi u/512)
#pragma unroll
    for (int k = 0; k < 4; ++k) {
      const float2 w1 = cmul(wu, E8c[k]);
      const float2 w2 = cmul(w1, w1);
      float2 tb = cmul(v[k][1], w2), td = cmul(v[k][3], w2);
      float2 a1 = cadd(v[k][0], tb), b1 = csub(v[k][0], tb);
      float2 cc = cadd(v[k][2], td), dd = csub(v[k][2], td);
      row[P(u + 64 * k)]       = cadd(a1, cmul(cc, w1));                          // s = u+64k
      row[P(u + 64 * k + 256)] = cadd(b1, cmul(dd, make_float2(-w1.y, w1.x)));    // s+256
    }
  }
  __syncthreads();

  // ---- store: scrambled proj.T.reshape layout (validated R1/R2):
  // sample s of row (bc, a'=2*(p0+r)) -> float2 idx 131072*(s>>5)+256*(16*(s&31)+bc)+p0+r
#pragma unroll
  for (int k = 0; k < 8; ++k) {
    int u2 = t + (k << 8);
    int r = u2 & 3, s = u2 >> 2;  // 0..511
    int o2 = 131072 * (s >> 5) + 256 * (16 * (s & 31) + bc) + p0 + r;
    out2[o2] = data[r][P(s)];
  }
}

extern "C" void kernel_launch(void* const* d_in, const int* in_sizes, int n_in,
                              void* d_out, int out_size, void* d_ws, size_t ws_size,
                              hipStream_t stream) {
  const float* x = (const float*)d_in[0];
  // d_in[1] = twiddle_fft, d_in[2] = twiddle_ifft (recomputed on the fly)
  const float* filt = (const float*)d_in[3];
  float* out = (float*)d_out;
  (void)in_sizes; (void)n_in; (void)out_size; (void)d_ws; (void)ws_size;

  hipLaunchKernelGGL(fbp_butterfly_wv, dim3(1024), dim3(THREADS), 0, stream,
                     x, filt, out);
}